// Round 6
// baseline (98.766 us; speedup 1.0000x reference)
//
#include <hip/hip_runtime.h>
#include <hip/hip_bf16.h>
#include <stdint.h>

// ---------------------------------------------------------------------------
// MatrixDFTLayer: out[b,k,c] = sum_n x[b,n] * (c==0 ? R : I)[k,n]
// == C[16384 x 2048] = A[16384 x 1024] * Beff^T  (Beff row-interleaved R/I)
// R6: BK=32 -> 64 KiB LDS -> 2 CO-RESIDENT blocks/CU (grid 512 = 2/CU, one
// round). Block A's epilogue-store burst / barriers / lgkm waits overlap
// block B's MFMA (m114). R3's NaN was launch_bounds(512,4): VGPR cap 128 <
// acc(128)+addr -> spills -> spill vmem ops corrupted the counted-vmcnt
// ledger. Here (512,2): natural ~104 VGPR, spill-free, 16 waves/CU.
// Ledger = R5-validated shape at 2 phases: q0 stages B1,A0,A1(t+1);
// q1 stages B0(t+2) into current buf (WAR-safe after q0's closing barrier),
// waits vmcnt(1) (5 outstanding -> retires exactly tile t+1's 4).
// ---------------------------------------------------------------------------

typedef __bf16 bf16x8 __attribute__((ext_vector_type(8)));
typedef float f32x4 __attribute__((ext_vector_type(4)));
typedef unsigned short ushort8 __attribute__((ext_vector_type(8)));

#define M_DIM   16384
#define N_OUT   2048
#define K_DIM   1024
#define NT      32            // K tiles of BK=32
#define X_ELEMS 16777216ull   // 16384*1024
#define B_ELEMS 2097152ull    // 2048*1024

__device__ __forceinline__ unsigned short f2bf(float f) {
    union { float f; unsigned u; } v; v.f = f;
    unsigned r = v.u + 0x7fffu + ((v.u >> 16) & 1u);   // RTNE
    return (unsigned short)(r >> 16);
}

// ---- pre-pass: convert x -> bf16, gather-interleave R/I -> Beff (bf16) ----
__global__ __launch_bounds__(256) void convert_kernel(
    const float* __restrict__ x, const float* __restrict__ R,
    const float* __restrict__ Im,
    unsigned short* __restrict__ xa, unsigned short* __restrict__ Beff)
{
    size_t idx = ((size_t)blockIdx.x * 256 + threadIdx.x) * 8;
    const float* src;
    unsigned short* dst;
    if (idx < X_ELEMS) {
        src = x + idx;
        dst = xa + idx;
    } else {
        size_t t = idx - X_ELEMS;          // linear index in Beff
        size_t j = t >> 10, n = t & 1023;  // Beff row j, col n
        src = ((j & 1) ? Im : R) + (j >> 1) * 1024 + n;
        dst = Beff + t;
    }
    float4 f0 = *(const float4*)src;
    float4 f1 = *(const float4*)(src + 4);
    ushort8 o;
    o[0] = f2bf(f0.x); o[1] = f2bf(f0.y); o[2] = f2bf(f0.z); o[3] = f2bf(f0.w);
    o[4] = f2bf(f1.x); o[5] = f2bf(f1.y); o[6] = f2bf(f1.z); o[7] = f2bf(f1.w);
    *(ushort8*)dst = o;
}

#define GLOAD_LDS16(g, l) \
    __builtin_amdgcn_global_load_lds( \
        (const __attribute__((address_space(1))) void*)(g), \
        (__attribute__((address_space(3))) void*)(l), 16, 0, 0)

// ---------------------------------------------------------------------------
// 256x256 tile, BK=32, 8 waves (2Mx4N), double-buffered 64 KiB LDS,
// 2 phases per K-tile. XOR swizzle for 64B rows: slot' = slot ^ ((row>>1)&3)
// (both-sides: pre-swizzled global source + same XOR on ds_read; LDS dest
// linear). Validated pre-timing in R3 (absmax 0.5).
// ---------------------------------------------------------------------------
__global__ __launch_bounds__(512, 2) void dft_gemm256(
    const unsigned short* __restrict__ A,   // [16384][1024] bf16 bits
    const unsigned short* __restrict__ B,   // [2048][1024]  bf16 bits
    float* __restrict__ C)                  // [16384][2048] fp32
{
    // [buf][op(0=A,1=B)][256 rows * 32 elems] -> 64 KiB total
    __shared__ __align__(16) unsigned short lds[2][2][8192];

    const int tid  = threadIdx.x;
    const int lane = tid & 63;
    const int w    = tid >> 6;          // wave 0..7
    const int wr   = w >> 2;            // 0..1 (M)
    const int wc   = w & 3;             // 0..3 (N)

    // XCD swizzle: nwg=512 divisible by 8
    const int bid = blockIdx.x;
    const int swz = (bid & 7) * 64 + (bid >> 3);
    const int tn  = swz & 7;            // 8 col tiles
    const int tm  = swz >> 3;           // 64 row tiles

    // ---- staging: one glds per 128x32-elem half (8 KB, 512 lanes x 16B) ---
    // thread t -> LDS row t>>2, 16B-slot t&3 (linear dest);
    // source col-slot pre-swizzled: slot ^ ((row>>1)&3), row = tid>>2
    const int srow = tid >> 2;
    const int scol = ((tid & 3) ^ ((tid >> 3) & 3)) * 8;
    const size_t a_row0 = (size_t)(tm * 256) * K_DIM;
    const size_t b_row0 = (size_t)(tn * 256) * K_DIM;

    auto stage_half = [&](int buf, int op, int half, int kt) {
        const unsigned short* g = (op ? B : A) + (op ? b_row0 : a_row0)
            + (size_t)(half * 128 + srow) * K_DIM + kt * 32 + scol;
        GLOAD_LDS16(g, &lds[buf][op][half * 4096 + w * 512]);
    };

    // ---- fragment reads: row = base + (lane&15), k-slot = lane>>4 ---------
    // swizzled elem offset within row: (slot ^ ((row>>1)&3)) * 8
    const int e    = ((lane >> 4) ^ ((lane >> 1) & 3)) * 8;
    const int arow = (wr * 128 + (lane & 15)) * 32;
    const int brow = (wc * 64  + (lane & 15)) * 32;

    f32x4 acc[8][4];
#pragma unroll
    for (int i = 0; i < 8; ++i)
#pragma unroll
        for (int j = 0; j < 4; ++j)
            acc[i][j] = (f32x4){0.f, 0.f, 0.f, 0.f};

    // ---- prologue: tile0 (4 glds) + B0(1) (1 glds); retire tile0 only ----
    stage_half(0, 1, 0, 0); stage_half(0, 1, 1, 0);
    stage_half(0, 0, 0, 0); stage_half(0, 0, 1, 0);
    stage_half(1, 1, 0, 1);
    asm volatile("s_waitcnt vmcnt(1)" ::: "memory");
    __builtin_amdgcn_s_barrier();

    bf16x8 af[4], bf[4];
    int buf = 0;
    for (int t = 0; t < NT; ++t) {
        const int nbuf = buf ^ 1;

        // ===== phase q0: acc[0-3][*]; 8 ds_read; stage B1,A0,A1 of t+1 =====
#pragma unroll
        for (int i = 0; i < 4; ++i)
            af[i] = *(const bf16x8*)&lds[buf][0][arow + i * 512 + e];
#pragma unroll
        for (int j = 0; j < 4; ++j)
            bf[j] = *(const bf16x8*)&lds[buf][1][brow + j * 512 + e];
        if (t + 1 < NT) {
            stage_half(nbuf, 1, 1, t + 1);      // B1(t+1)
            stage_half(nbuf, 0, 0, t + 1);      // A0(t+1)
            stage_half(nbuf, 0, 1, t + 1);      // A1(t+1)
        }
        __builtin_amdgcn_s_barrier();
        asm volatile("s_waitcnt lgkmcnt(0)" ::: "memory");
        __builtin_amdgcn_sched_barrier(0);
        __builtin_amdgcn_s_setprio(1);
#pragma unroll
        for (int i = 0; i < 4; ++i)
#pragma unroll
            for (int j = 0; j < 4; ++j)
                acc[i][j] = __builtin_amdgcn_mfma_f32_16x16x32_bf16(
                    af[i], bf[j], acc[i][j], 0, 0, 0);
        __builtin_amdgcn_s_setprio(0);
        __builtin_amdgcn_s_barrier();

        // ===== phase q1: acc[4-7][*]; 4 ds_read; stage B0(t+2); wait =====
#pragma unroll
        for (int i = 0; i < 4; ++i)
            af[i] = *(const bf16x8*)&lds[buf][0][arow + (i + 4) * 512 + e];
        // B0(t+2) -> B0[buf]: all waves' tile-t B-reads completed before q0's
        // closing barrier (each wave passed its own lgkmcnt(0) first).
        if (t + 2 < NT) stage_half(buf, 1, 0, t + 2);
        // outstanding: B0(t+1)[1] + B1,A0,A1(t+1)[3] + B0(t+2)[1] = 5
        // vmcnt(1) retires exactly tile t+1's 4; keeps B0(t+2) in flight
        if (t + 2 < NT)      asm volatile("s_waitcnt vmcnt(1)" ::: "memory");
        else if (t + 1 < NT) asm volatile("s_waitcnt vmcnt(0)" ::: "memory");
        __builtin_amdgcn_s_barrier();
        asm volatile("s_waitcnt lgkmcnt(0)" ::: "memory");
        __builtin_amdgcn_sched_barrier(0);
        __builtin_amdgcn_s_setprio(1);
#pragma unroll
        for (int i = 0; i < 4; ++i)
#pragma unroll
            for (int j = 0; j < 4; ++j)
                acc[i + 4][j] = __builtin_amdgcn_mfma_f32_16x16x32_bf16(
                    af[i], bf[j], acc[i + 4][j], 0, 0, 0);
        __builtin_amdgcn_s_setprio(0);
        __builtin_amdgcn_s_barrier();

        buf = nbuf;
    }

    // ---- epilogue: C/D layout col = lane&15, row = (lane>>4)*4 + reg ------
    const int crow0 = tm * 256 + wr * 128 + ((lane >> 4) << 2);
    const int ccol0 = tn * 256 + wc * 64 + (lane & 15);
#pragma unroll
    for (int i = 0; i < 8; ++i)
#pragma unroll
        for (int j = 0; j < 4; ++j) {
            float* cp = C + (size_t)(crow0 + i * 16) * N_OUT + ccol0 + j * 16;
#pragma unroll
            for (int r = 0; r < 4; ++r)
                cp[(size_t)r * N_OUT] = acc[i][j][r];
        }
}

// ---- fallback (only if d_ws is too small): naive fp32 ----
__global__ void naive_dft(const float* __restrict__ x, const float* __restrict__ R,
                          const float* __restrict__ Im, float* __restrict__ out)
{
    int gid = blockIdx.x * blockDim.x + threadIdx.x;
    int b = gid >> 10, k = gid & 1023;
    const float* xr = x + (size_t)b * 1024;
    const float* rr = R + (size_t)k * 1024;
    const float* ir = Im + (size_t)k * 1024;
    float sr = 0.f, si = 0.f;
    for (int n = 0; n < 1024; ++n) {
        float v = xr[n];
        sr += v * rr[n];
        si += v * ir[n];
    }
    out[(size_t)gid * 2]     = sr;
    out[(size_t)gid * 2 + 1] = si;
}

extern "C" void kernel_launch(void* const* d_in, const int* in_sizes, int n_in,
                              void* d_out, int out_size, void* d_ws, size_t ws_size,
                              hipStream_t stream)
{
    const float* x  = (const float*)d_in[0];
    const float* R  = (const float*)d_in[1];
    const float* Im = (const float*)d_in[2];
    float* out = (float*)d_out;

    const size_t need = (X_ELEMS + B_ELEMS) * sizeof(unsigned short); // 37.75 MB
    if (ws_size >= need) {
        unsigned short* xa   = (unsigned short*)d_ws;
        unsigned short* Beff = xa + X_ELEMS;
        const int conv_blocks = (int)((X_ELEMS + B_ELEMS) / 8 / 256); // 9216
        convert_kernel<<<conv_blocks, 256, 0, stream>>>(x, R, Im, xa, Beff);
        dft_gemm256<<<512, 512, 0, stream>>>(xa, Beff, out);
    } else {
        naive_dft<<<(M_DIM * K_DIM) / 256, 256, 0, stream>>>(x, R, Im, out);
    }
}

// Round 7
// 69.970 us; speedup vs baseline: 1.4116x; 1.4116x over previous
//
#include <hip/hip_runtime.h>
#include <hip/hip_bf16.h>
#include <stdint.h>

// ---------------------------------------------------------------------------
// MatrixDFTLayer: out[b,k,c] = sum_n x[b,n] * (c==0 ? R : I)[k,n],  x REAL.
// Hermitian symmetry: Y[1024-k] = conj(Y[k])  ->  GEMM only k=0..511
// (Beff = 1024 rows, HALF the FLOPs), epilogue mirror-writes k'=1024-k with
// negated imag. Nyquist k=512 (cos=(-1)^n, sin=0) fused into convert kernel.
// Grid 256 = exactly 1 block/CU, ONE round (was 2).
// GEMM = R2-validated 256x256/BK=64/4-phase skeleton, sync structure
// UNCHANGED (R4/R5/R6 lesson: schedule variants all neutral-to-worse).
// ---------------------------------------------------------------------------

typedef __bf16 bf16x8 __attribute__((ext_vector_type(8)));
typedef float f32x4 __attribute__((ext_vector_type(4)));
typedef unsigned short ushort8 __attribute__((ext_vector_type(8)));

#define M_DIM   16384
#define N_OUT   2048          // C row stride (floats)
#define K_DIM   1024
#define NT      16            // K tiles of BK=64
#define X_ELEMS 16777216ull   // 16384*1024
#define BH_ELEMS 1048576ull   // 1024*1024 (half-spectrum Beff)

__device__ __forceinline__ unsigned short f2bf(float f) {
    union { float f; unsigned u; } v; v.f = f;
    unsigned r = v.u + 0x7fffu + ((v.u >> 16) & 1u);   // RTNE
    return (unsigned short)(r >> 16);
}

// ---- pre-pass: x->bf16, gather k<512 rows of R/I -> Beff, fused Nyquist ---
// Blocks 0..8191 cover x (2048 elems = exactly 2 rows/block) and also
// compute yr[b,512] = sum_n x[b,n]*(-1)^n  (yi[b,512] = 0).
__global__ __launch_bounds__(256) void convert_kernel(
    const float* __restrict__ x, const float* __restrict__ R,
    const float* __restrict__ Im,
    unsigned short* __restrict__ xa, unsigned short* __restrict__ Beff,
    float* __restrict__ C)
{
    __shared__ float nsum[4];
    size_t idx = ((size_t)blockIdx.x * 256 + threadIdx.x) * 8;
    const float* src;
    unsigned short* dst;
    if (idx < X_ELEMS) {
        src = x + idx;
        dst = xa + idx;
    } else {
        size_t t = idx - X_ELEMS;          // linear index in Beff (1024x1024)
        size_t j = t >> 10, n = t & 1023;  // Beff row j = 2k+c, col n
        src = ((j & 1) ? Im : R) + (j >> 1) * 1024 + n;
        dst = Beff + t;
    }
    float4 f0 = *(const float4*)src;
    float4 f1 = *(const float4*)(src + 4);
    ushort8 o;
    o[0] = f2bf(f0.x); o[1] = f2bf(f0.y); o[2] = f2bf(f0.z); o[3] = f2bf(f0.w);
    o[4] = f2bf(f1.x); o[5] = f2bf(f1.y); o[6] = f2bf(f1.z); o[7] = f2bf(f1.w);
    *(ushort8*)dst = o;

    // ---- fused Nyquist (x-covering blocks only; uniform per block) --------
    if (blockIdx.x < 8192) {
        // alternating-sign partial over this thread's 8 elems (n parity = e)
        float s = f0.x - f0.y + f0.z - f0.w + f1.x - f1.y + f1.z - f1.w;
#pragma unroll
        for (int m = 32; m >= 1; m >>= 1)
            s += __shfl_xor(s, m, 64);
        const int w = threadIdx.x >> 6;     // wave 0..3
        if ((threadIdx.x & 63) == 0) nsum[w] = s;
        __syncthreads();
        // rows 2b (waves 0,1) and 2b+1 (waves 2,3)
        if (threadIdx.x == 0) {
            size_t row = (size_t)blockIdx.x * 2;
            C[row * N_OUT + 1024] = nsum[0] + nsum[1];
            C[row * N_OUT + 1025] = 0.0f;
        }
        if (threadIdx.x == 128) {
            size_t row = (size_t)blockIdx.x * 2 + 1;
            C[row * N_OUT + 1024] = nsum[2] + nsum[3];
            C[row * N_OUT + 1025] = 0.0f;
        }
    }
}

#define GLOAD_LDS16(g, l) \
    __builtin_amdgcn_global_load_lds( \
        (const __attribute__((address_space(1))) void*)(g), \
        (__attribute__((address_space(3))) void*)(l), 16, 0, 0)

// ---------------------------------------------------------------------------
// 256x256 tile, BK=64, 8 waves (2Mx4N), double-buffered LDS (128 KiB),
// 4 phases/K-tile, R2-validated staging ledger: B1(t+1)@q0, A0(t+1)@q1,
// A1(t+1)@q2, B0(t+2)@q3, vmcnt(2)@q3. XOR swizzle both-sides.
// Grid 256 (64 tm x 4 tn), one round. Epilogue: primary + Hermitian mirror.
// ---------------------------------------------------------------------------
__global__ __launch_bounds__(512, 1) void dft_gemm256(
    const unsigned short* __restrict__ A,   // [16384][1024] bf16 bits
    const unsigned short* __restrict__ B,   // [1024][1024]  bf16 bits
    float* __restrict__ C)                  // [16384][2048] fp32
{
    __shared__ __align__(16) unsigned short lds[2][2][16384];

    const int tid  = threadIdx.x;
    const int lane = tid & 63;
    const int w    = tid >> 6;          // wave 0..7
    const int wr   = w >> 2;            // 0..1 (M)
    const int wc   = w & 3;             // 0..3 (N)

    // XCD swizzle: nwg=256 divisible by 8; 4 tn-blocks of one tm share an XCD
    const int bid = blockIdx.x;
    const int swz = (bid & 7) * 32 + (bid >> 3);
    const int tn  = swz & 3;            // 4 col tiles (1024/256)
    const int tm  = swz >> 2;           // 64 row tiles

    // ---- staging constants (pre-swizzled global source, linear LDS dest) --
    const int r3    = lane >> 3;                                   // row&7
    const int fx_w  = ((r3 & 3) << 4) | (((r3 >> 2) & 1) << 6);    // byte xor
    const int scol  = ((((lane & 7) * 16) ^ fx_w) >> 1);           // elem col
    const int srow  = w * 8 + r3;                                  // row in 64-chunk
    const size_t a_row0 = (size_t)(tm * 256) * K_DIM;
    const size_t b_row0 = (size_t)(tn * 256) * K_DIM;

    auto stage_half = [&](int buf, int op, int half, int kt) {
        const unsigned short* g = (op ? B : A) + (op ? b_row0 : a_row0)
            + (size_t)(half * 128 + srow) * K_DIM + kt * 64 + scol;
        unsigned short* l0 = &lds[buf][op][half * 8192 + w * 512];
        GLOAD_LDS16(g,              l0);
        GLOAD_LDS16(g + 64 * K_DIM, l0 + 4096);
    };

    // ---- fragment-read constants (swizzled ds_read) -----------------------
    const int fx_r = ((lane & 3) << 4) | (((lane >> 2) & 1) << 6);
    const int e0   = ((((lane >> 4) & 3) * 16) ^ fx_r) >> 1;        // ks0 elem
    const int e1   = ((64 + ((lane >> 4) & 3) * 16) ^ fx_r) >> 1;   // ks1 elem
    const int arow = (wr * 128 + (lane & 15)) * 64;
    const int brow = (wc * 64  + (lane & 15)) * 64;

    f32x4 acc[8][4];
#pragma unroll
    for (int i = 0; i < 8; ++i)
#pragma unroll
        for (int j = 0; j < 4; ++j)
            acc[i][j] = (f32x4){0.f, 0.f, 0.f, 0.f};

    // ---- prologue: tile0 (8 glds) + B0(1) (2 glds); retire tile0 only ----
    stage_half(0, 0, 0, 0); stage_half(0, 0, 1, 0);
    stage_half(0, 1, 0, 0); stage_half(0, 1, 1, 0);
    stage_half(1, 1, 0, 1);
    asm volatile("s_waitcnt vmcnt(2)" ::: "memory");
    __builtin_amdgcn_s_barrier();

    bf16x8 af[4], bf[4];
    int buf = 0;
    for (int t = 0; t < NT; ++t) {
        const int nbuf = buf ^ 1;

        // ===== phase q0: acc[0-3][*] ks0; stage B1(t+1) =====
#pragma unroll
        for (int i = 0; i < 4; ++i)
            af[i] = *(const bf16x8*)&lds[buf][0][arow + i * 1024 + e0];
#pragma unroll
        for (int j = 0; j < 4; ++j)
            bf[j] = *(const bf16x8*)&lds[buf][1][brow + j * 1024 + e0];
        if (t + 1 < NT) stage_half(nbuf, 1, 1, t + 1);
        __builtin_amdgcn_s_barrier();
        asm volatile("s_waitcnt lgkmcnt(0)" ::: "memory");
        __builtin_amdgcn_sched_barrier(0);
        __builtin_amdgcn_s_setprio(1);
#pragma unroll
        for (int i = 0; i < 4; ++i)
#pragma unroll
            for (int j = 0; j < 4; ++j)
                acc[i][j] = __builtin_amdgcn_mfma_f32_16x16x32_bf16(
                    af[i], bf[j], acc[i][j], 0, 0, 0);
        __builtin_amdgcn_s_setprio(0);
        __builtin_amdgcn_s_barrier();

        // ===== phase q1: acc[4-7][*] ks0; stage A0(t+1) =====
#pragma unroll
        for (int i = 0; i < 4; ++i)
            af[i] = *(const bf16x8*)&lds[buf][0][arow + (i + 4) * 1024 + e0];
        if (t + 1 < NT) stage_half(nbuf, 0, 0, t + 1);
        __builtin_amdgcn_s_barrier();
        asm volatile("s_waitcnt lgkmcnt(0)" ::: "memory");
        __builtin_amdgcn_sched_barrier(0);
        __builtin_amdgcn_s_setprio(1);
#pragma unroll
        for (int i = 0; i < 4; ++i)
#pragma unroll
            for (int j = 0; j < 4; ++j)
                acc[i + 4][j] = __builtin_amdgcn_mfma_f32_16x16x32_bf16(
                    af[i], bf[j], acc[i + 4][j], 0, 0, 0);
        __builtin_amdgcn_s_setprio(0);
        __builtin_amdgcn_s_barrier();

        // ===== phase q2: acc[0-3][*] ks1; stage A1(t+1) =====
#pragma unroll
        for (int i = 0; i < 4; ++i)
            af[i] = *(const bf16x8*)&lds[buf][0][arow + i * 1024 + e1];
#pragma unroll
        for (int j = 0; j < 4; ++j)
            bf[j] = *(const bf16x8*)&lds[buf][1][brow + j * 1024 + e1];
        if (t + 1 < NT) stage_half(nbuf, 0, 1, t + 1);
        __builtin_amdgcn_s_barrier();
        asm volatile("s_waitcnt lgkmcnt(0)" ::: "memory");
        __builtin_amdgcn_sched_barrier(0);
        __builtin_amdgcn_s_setprio(1);
#pragma unroll
        for (int i = 0; i < 4; ++i)
#pragma unroll
            for (int j = 0; j < 4; ++j)
                acc[i][j] = __builtin_amdgcn_mfma_f32_16x16x32_bf16(
                    af[i], bf[j], acc[i][j], 0, 0, 0);
        __builtin_amdgcn_s_setprio(0);
        __builtin_amdgcn_s_barrier();

        // ===== phase q3: acc[4-7][*] ks1; stage B0(t+2); counted wait =====
#pragma unroll
        for (int i = 0; i < 4; ++i)
            af[i] = *(const bf16x8*)&lds[buf][0][arow + (i + 4) * 1024 + e1];
        if (t + 2 < NT) stage_half(buf, 1, 0, t + 2);
        // outstanding: tile t+1's 8 + B0(t+2)'s 2 -> vmcnt(2) retires t+1
        if (t + 2 < NT)      asm volatile("s_waitcnt vmcnt(2)" ::: "memory");
        else if (t + 1 < NT) asm volatile("s_waitcnt vmcnt(0)" ::: "memory");
        __builtin_amdgcn_s_barrier();
        asm volatile("s_waitcnt lgkmcnt(0)" ::: "memory");
        __builtin_amdgcn_sched_barrier(0);
        __builtin_amdgcn_s_setprio(1);
#pragma unroll
        for (int i = 0; i < 4; ++i)
#pragma unroll
            for (int j = 0; j < 4; ++j)
                acc[i + 4][j] = __builtin_amdgcn_mfma_f32_16x16x32_bf16(
                    af[i], bf[j], acc[i + 4][j], 0, 0, 0);
        __builtin_amdgcn_s_setprio(0);
        __builtin_amdgcn_s_barrier();

        buf = nbuf;
    }

    // ---- epilogue: primary (cols 0..1023) + Hermitian mirror --------------
    // C/D layout: col = lane&15, row = (lane>>4)*4 + reg  [m89]
    // col j=2k+c -> mirror m = 2*(1024-k)+c = 2048 - j + 2*(j&1), valid j>=2
    const int crow0 = tm * 256 + wr * 128 + ((lane >> 4) << 2);
    const int ccol0 = tn * 256 + wc * 64 + (lane & 15);
#pragma unroll
    for (int i = 0; i < 8; ++i)
#pragma unroll
        for (int j = 0; j < 4; ++j) {
            const int   col   = ccol0 + j * 16;
            const int   mcol  = 2048 - col + 2 * (col & 1);
            const float msign = (col & 1) ? -1.0f : 1.0f;
            const bool  do_m  = (col >= 2);
            float* cp = C + (size_t)(crow0 + i * 16) * N_OUT + col;
            float* mp = C + (size_t)(crow0 + i * 16) * N_OUT + mcol;
#pragma unroll
            for (int r = 0; r < 4; ++r) {
                cp[(size_t)r * N_OUT] = acc[i][j][r];
                if (do_m) mp[(size_t)r * N_OUT] = msign * acc[i][j][r];
            }
        }
}

// ---- fallback (only if d_ws is too small): naive fp32 ----
__global__ void naive_dft(const float* __restrict__ x, const float* __restrict__ R,
                          const float* __restrict__ Im, float* __restrict__ out)
{
    int gid = blockIdx.x * blockDim.x + threadIdx.x;
    int b = gid >> 10, k = gid & 1023;
    const float* xr = x + (size_t)b * 1024;
    const float* rr = R + (size_t)k * 1024;
    const float* ir = Im + (size_t)k * 1024;
    float sr = 0.f, si = 0.f;
    for (int n = 0; n < 1024; ++n) {
        float v = xr[n];
        sr += v * rr[n];
        si += v * ir[n];
    }
    out[(size_t)gid * 2]     = sr;
    out[(size_t)gid * 2 + 1] = si;
}

extern "C" void kernel_launch(void* const* d_in, const int* in_sizes, int n_in,
                              void* d_out, int out_size, void* d_ws, size_t ws_size,
                              hipStream_t stream)
{
    const float* x  = (const float*)d_in[0];
    const float* R  = (const float*)d_in[1];
    const float* Im = (const float*)d_in[2];
    float* out = (float*)d_out;

    const size_t need = (X_ELEMS + BH_ELEMS) * sizeof(unsigned short); // 35.7 MB
    if (ws_size >= need) {
        unsigned short* xa   = (unsigned short*)d_ws;
        unsigned short* Beff = xa + X_ELEMS;
        const int conv_blocks = (int)((X_ELEMS + BH_ELEMS) / 8 / 256); // 8704
        convert_kernel<<<conv_blocks, 256, 0, stream>>>(x, R, Im, xa, Beff, out);
        dft_gemm256<<<256, 512, 0, stream>>>(xa, Beff, out);
    } else {
        naive_dft<<<(M_DIM * K_DIM) / 256, 256, 0, stream>>>(x, R, Im, out);
    }
}